// Round 8
// baseline (516.787 us; speedup 1.0000x reference)
//
#include <hip/hip_runtime.h>
#include <math.h>

static constexpr int   B_    = 8;
static constexpr int   N_    = 2048;   // points per set
static constexpr int   TPB   = 256;
static constexpr int   TILE  = 16;     // rows per block per batch
static constexpr int   NPBAR = 128;    // blocks participating per batch barrier
static constexpr int   NBLK  = 512;
static constexpr int   BN    = B_ * N_;
static constexpr float EPS_  = 1e-9f;
static constexpr float LOG2E = 1.4426950408889634f;

#define SCOPE_A __HIP_MEMORY_SCOPE_AGENT

// ws layout (floats):
//  X1 [4*BN]  packed xyz1 (x,y,z,|p|^2)  read-only after init
//  X2 [4*BN]  packed xyz2                read-only after init
//  LSCAL[BN] LSATR[BN] LWR[BN] WR[BN]    cross-block state (relaxed sc-ops)
//  BAR [8*32 u32]                        per-batch monotonic barrier counters
#define WS_X1    (ws)
#define WS_X2    (ws + 4*BN)
#define WS_LSCAL (ws + 8*BN)
#define WS_LSATR (ws + 9*BN)
#define WS_LWR   (ws + 10*BN)
#define WS_WR    (ws + 11*BN)
#define WS_BARU  ((unsigned*)(ws + 12*BN))

__device__ __constant__ float c_lvl[11] = {
    -65536.f*LOG2E, -16384.f*LOG2E, -4096.f*LOG2E, -1024.f*LOG2E,
    -256.f*LOG2E,   -64.f*LOG2E,    -16.f*LOG2E,   -4.f*LOG2E,
    -1.f*LOG2E,     -0.25f*LOG2E,   0.f };

__device__ __forceinline__ float aload(const float* p) {
    return __hip_atomic_load(p, __ATOMIC_RELAXED, SCOPE_A);
}
__device__ __forceinline__ void astore(float* p, float v) {
    __hip_atomic_store(p, v, __ATOMIC_RELAXED, SCOPE_A);
}

__global__ void __launch_bounds__(TPB)
emd_init(const float* __restrict__ xyz1, const float* __restrict__ xyz2,
         float* __restrict__ ws)
{
    const int idx = blockIdx.x * TPB + threadIdx.x;
    if (idx < BN) {
        float x = xyz1[idx*3], y = xyz1[idx*3+1], z = xyz1[idx*3+2];
        reinterpret_cast<float4*>(WS_X1)[idx] =
            make_float4(x, y, z, fmaf(x,x, fmaf(y,y, z*z)));
        x = xyz2[idx*3]; y = xyz2[idx*3+1]; z = xyz2[idx*3+2];
        reinterpret_cast<float4*>(WS_X2)[idx] =
            make_float4(x, y, z, fmaf(x,x, fmaf(y,y, z*z)));
    }
    if (idx < 8 * 32) WS_BARU[idx] = 0u;   // re-zero every launch (monotonic)
}

// ---- fence-free split barrier (round-7 mechanism, arrive/wait decoupled) ----
__device__ __forceinline__ void b_arrive(unsigned* cnt)
{
    if (threadIdx.x == 0)
        __hip_atomic_fetch_add(cnt, 1u, __ATOMIC_RELEASE, SCOPE_A);
}
__device__ __forceinline__ void b_wait(unsigned* cnt, unsigned target)
{
    if (threadIdx.x == 0) {
        int spins = 0;
        while (__hip_atomic_load(cnt, __ATOMIC_RELAXED, SCOPE_A) < target) {
            __builtin_amdgcn_s_sleep(4);
            if (++spins > (1 << 17)) break;   // fail visibly, never hang
        }
        __builtin_amdgcn_fence(__ATOMIC_ACQUIRE, "workgroup");
    }
    __syncthreads();
}

// ---- block reduction: 128x16 partials -> 16 row sums (valid in t < TILE) ----
// scratch = 2048-float LDS region (overlays the aux array; sync-guarded)
__device__ __forceinline__ float reduce16(float* scratch, const float (&s)[8],
                                          int t)
{
    float (*red)[16] = reinterpret_cast<float(*)[16]>(scratch);
    __syncthreads();                       // prior readers of scratch/pts done
    const int c = t >> 1, g = t & 1;
#pragma unroll
    for (int j = 0; j < 8; ++j) red[c][g*8 + j] = s[j];
    __syncthreads();
    const int col = t & 15, rg = t >> 4;
    float v = 0.f;
#pragma unroll
    for (int r = 0; r < 8; ++r) v += red[rg*8 + r][col];
    v += __shfl_xor(v, 16, 64);
    v += __shfl_xor(v, 32, 64);            // lanes<16 per wave: 4-rg partial
    __syncthreads();
    if ((t & 63) < 16) scratch[(t >> 6)*16 + col] = v;
    __syncthreads();
    float rs = 0.f;
    if (t < TILE) {
#pragma unroll
        for (int w = 0; w < 4; ++w) rs += scratch[w*16 + t];
    }
    return rs;
}

// ---- sweeps (16 iters, 8 owned rows/cols per thread, 2-deep prefetch) ----
__device__ __forceinline__ void sweep01(const float4* pts,
    const float (&kx)[8], const float (&ky)[8], const float (&kz)[8],
    const float (&kq)[8], int t, float (&s1)[8])
{
#pragma unroll
    for (int j = 0; j < 8; ++j) s1[j] = 0.f;
    int l = t >> 1;
    float4 p = pts[l];
#pragma unroll 4
    for (int i = 0; i < 16; ++i) {
        const int ln = (l + 128) & (N_ - 1);
        const float4 pn = pts[ln];
#pragma unroll
        for (int j = 0; j < 8; ++j) {
            const float arg = fmaf(kx[j], p.x, fmaf(ky[j], p.y,
                              fmaf(kz[j], p.z, p.w + kq[j])));
            s1[j] += __builtin_amdgcn_exp2f(arg);
        }
        p = pn; l = ln;
    }
}

__device__ __forceinline__ void sweep2(const float4* pts, const float* aux,
    const float (&kx)[8], const float (&ky)[8], const float (&kz)[8],
    const float (&kq)[8], float lvA, float lvB, int t,
    float (&s1)[8], float (&s2)[8], float (&s3)[8])
{
#pragma unroll
    for (int j = 0; j < 8; ++j) { s1[j] = 0.f; s2[j] = 0.f; s3[j] = 0.f; }
    int l = t >> 1;
    float4 p = pts[l];
    float  a = aux[l];
#pragma unroll 2
    for (int i = 0; i < 16; ++i) {
        const int ln = (l + 128) & (N_ - 1);
        const float4 pn = pts[ln];
        const float  an = aux[ln];
        const float p2 = fmaf(p.x, p.x, fmaf(p.y, p.y, p.z * p.z));
#pragma unroll
        for (int j = 0; j < 8; ++j) {
            const float dq = fmaf(kx[j], p.x, fmaf(ky[j], p.y,
                             fmaf(kz[j], p.z, kq[j])));    // |q|^2 - 2 p.q
            const float sq = __builtin_amdgcn_sqrtf(fmaxf(dq + p2, 0.f));
            const float eA = __builtin_amdgcn_exp2f(fmaf(lvA, dq, p.w));
            const float eB = __builtin_amdgcn_exp2f(fmaf(lvB, dq, a));
            s1[j] += eA;
            s2[j]  = fmaf(eA, sq, s2[j]);
            s3[j] += eB;
        }
        p = pn; a = an; l = ln;
    }
}

__device__ __forceinline__ void sweep3(const float4* pts,
    const float (&kx)[8], const float (&ky)[8], const float (&kz)[8],
    int t, float (&s2)[8])
{
#pragma unroll
    for (int j = 0; j < 8; ++j) s2[j] = 0.f;
    int l = t >> 1;
    float4 p = pts[l];
#pragma unroll 4
    for (int i = 0; i < 16; ++i) {
        const int ln = (l + 128) & (N_ - 1);
        const float4 pn = pts[ln];
#pragma unroll
        for (int j = 0; j < 8; ++j) {
            const float dx = p.x - kx[j], dy = p.y - ky[j], dz = p.z - kz[j];
            const float d2 = fmaf(dx, dx, fmaf(dy, dy, dz * dz));
            s2[j] = fmaf(p.w, __builtin_amdgcn_sqrtf(fmaxf(d2, 0.f)), s2[j]);
        }
        p = pn; l = ln;
    }
}

// ---- per-batch context ----
struct Ctx {
    const float4* x1v;   // batch-offset packed clouds
    const float4* x2v;
    float *lscal, *lsatr, *lwr, *wrp;   // batch-offset state arrays
    float4* pts;         // 2048 float4 LDS
    float*  aux;         // 2048 float  LDS (M2 second arg / reduce scratch)
    unsigned* cnt;       // barrier counter
    float satl, satr, mysc, cost;       // meaningful in t < TILE
};

__device__ __forceinline__ void phase_M0(Ctx& C, int tile, int t)
{
    const float lv = c_lvl[0];
    float kx[8], ky[8], kz[8], kq[8];
    const int ob = tile * TILE + (t & 1) * 8;
#pragma unroll
    for (int j = 0; j < 8; ++j) {
        float4 v = C.x1v[ob + j];
        kx[j] = -2.f*lv*v.x; ky[j] = -2.f*lv*v.y; kz[j] = -2.f*lv*v.z;
        kq[j] = lv * v.w;
    }
    for (int p = t; p < N_; p += TPB) {
        float4 v = C.x2v[p];
        C.pts[p] = make_float4(v.x, v.y, v.z, lv * v.w);   // lsatr = 0 initially
    }
    __syncthreads();
    float s1[8];
    sweep01(C.pts, kx, ky, kz, kq, t, s1);
    const float rs1 = reduce16(C.aux, s1, t);
    if (t < TILE) {
        C.mysc = C.satl / (rs1 + EPS_);
        astore(C.lscal + tile * TILE + t, __log2f(C.mysc));
    }
}

__device__ __forceinline__ void phase_M1(Ctx& C, int tile, int t, int lev)
{
    const float lv = c_lvl[lev];
    float kx[8], ky[8], kz[8], kq[8];
    const int ob = tile * TILE + (t & 1) * 8;
#pragma unroll
    for (int j = 0; j < 8; ++j) {
        float4 v = C.x2v[ob + j];                 // own cols (set 2)
        kx[j] = -2.f*lv*v.x; ky[j] = -2.f*lv*v.y; kz[j] = -2.f*lv*v.z;
        kq[j] = lv * v.w;
    }
    for (int p = t; p < N_; p += TPB) {
        float4 v = C.x1v[p];
        C.pts[p] = make_float4(v.x, v.y, v.z,
                               fmaf(lv, v.w, aload(C.lscal + p)));
    }
    __syncthreads();
    float s1[8];
    sweep01(C.pts, kx, ky, kz, kq, t, s1);
    const float rs1 = reduce16(C.aux, s1, t);
    if (t < TILE) {
        const int gi   = tile * TILE + t;
        const float w1s = C.satr * rs1;
        const float rr  = fminf(C.satr / (w1s + EPS_), 1.f);
        const float wrv = C.satr * rr;
        C.satr = fmaxf(C.satr - rr * w1s, 0.f);
        astore(C.wrp   + gi, wrv);
        astore(C.lwr   + gi, __log2f(wrv));
        astore(C.lsatr + gi, __log2f(C.satr));
    }
}

__device__ __forceinline__ void phase_M2(Ctx& C, int tile, int t, int lev)
{
    const float lvA = c_lvl[lev], lvB = c_lvl[lev + 1];
    float kx[8], ky[8], kz[8], kq[8];
    const int ob = tile * TILE + (t & 1) * 8;
#pragma unroll
    for (int j = 0; j < 8; ++j) {
        float4 v = C.x1v[ob + j];                 // own rows (set 1)
        kx[j] = -2.f*v.x; ky[j] = -2.f*v.y; kz[j] = -2.f*v.z; kq[j] = v.w;
    }
    for (int p = t; p < N_; p += TPB) {
        float4 v = C.x2v[p];
        C.pts[p] = make_float4(v.x, v.y, v.z,
                               fmaf(lvA, v.w, aload(C.lwr + p)));
        C.aux[p] = fmaf(lvB, v.w, aload(C.lsatr + p));
    }
    __syncthreads();
    float s1[8], s2[8], s3[8];
    sweep2(C.pts, C.aux, kx, ky, kz, kq, lvA, lvB, t, s1, s2, s3);
    const float rs1 = reduce16(C.aux, s1, t);
    const float rs2 = reduce16(C.aux, s2, t);
    const float rs3 = reduce16(C.aux, s3, t);
    if (t < TILE) {
        C.satl = fmaxf(C.satl - C.mysc * rs1, 0.f);
        C.cost = fmaf(C.mysc, rs2, C.cost);
        C.mysc = C.satl / (rs3 + EPS_);
        astore(C.lscal + tile * TILE + t, __log2f(C.mysc));
    }
}

__device__ __forceinline__ void phase_M3(Ctx& C, int tile, int t, int batch,
                                         float* out)
{
    float kx[8], ky[8], kz[8];
    const int ob = tile * TILE + (t & 1) * 8;
#pragma unroll
    for (int j = 0; j < 8; ++j) {
        float4 v = C.x1v[ob + j];
        kx[j] = v.x; ky[j] = v.y; kz[j] = v.z;
    }
    for (int p = t; p < N_; p += TPB) {
        float4 v = C.x2v[p];
        C.pts[p] = make_float4(v.x, v.y, v.z, aload(C.wrp + p));
    }
    __syncthreads();
    float s2[8];
    sweep3(C.pts, kx, ky, kz, t, s2);
    const float rs2 = reduce16(C.aux, s2, t);
    float v = (t < TILE) ? fmaf(C.mysc, rs2, C.cost) : 0.f;
#pragma unroll
    for (int k = 8; k >= 1; k >>= 1) v += __shfl_xor(v, k, 16);
    if (t == 0) atomicAdd(out + batch, v);
}

__global__ void __launch_bounds__(TPB, 2)
emd_main(float* __restrict__ ws, float* __restrict__ out)
{
    __shared__ __align__(16) float4 ptsA[N_];   // 32 KB
    __shared__ __align__(16) float4 ptsB[N_];   // 32 KB
    __shared__ float auxA[N_];                  // 8 KB
    __shared__ float auxB[N_];                  // 8 KB   (total 80 KB exact)

    const int pid  = blockIdx.x >> 7;           // 0..3
    const int tile = blockIdx.x & 127;          // 0..127
    const int t    = threadIdx.x;
    const int bA   = pid, bB = pid + 4;

    Ctx A, Bc;
    A.x1v  = reinterpret_cast<const float4*>(WS_X1) + bA * N_;
    A.x2v  = reinterpret_cast<const float4*>(WS_X2) + bA * N_;
    A.lscal = WS_LSCAL + bA * N_;  A.lsatr = WS_LSATR + bA * N_;
    A.lwr   = WS_LWR   + bA * N_;  A.wrp   = WS_WR    + bA * N_;
    A.pts = ptsA; A.aux = auxA; A.cnt = WS_BARU + bA * 32;
    A.satl = 1.f; A.satr = 1.f; A.mysc = 0.f; A.cost = 0.f;

    Bc.x1v  = reinterpret_cast<const float4*>(WS_X1) + bB * N_;
    Bc.x2v  = reinterpret_cast<const float4*>(WS_X2) + bB * N_;
    Bc.lscal = WS_LSCAL + bB * N_; Bc.lsatr = WS_LSATR + bB * N_;
    Bc.lwr   = WS_LWR   + bB * N_; Bc.wrp   = WS_WR    + bB * N_;
    Bc.pts = ptsB; Bc.aux = auxB; Bc.cnt = WS_BARU + bB * 32;
    Bc.satl = 1.f; Bc.satr = 1.f; Bc.mysc = 0.f; Bc.cost = 0.f;

    unsigned phA = 0, phB = 0;

    // prologue: M0 on both batches
    phase_M0(A, tile, t);  b_arrive(A.cnt);  ++phA;
    phase_M0(Bc, tile, t); b_arrive(Bc.cnt); ++phB;
    b_wait(A.cnt, NPBAR * phA);

    for (int lev = 0; lev <= 10; ++lev) {
        phase_M1(A, tile, t, lev);  b_arrive(A.cnt);  ++phA;
        b_wait(Bc.cnt, NPBAR * phB);
        phase_M1(Bc, tile, t, lev); b_arrive(Bc.cnt); ++phB;
        b_wait(A.cnt, NPBAR * phA);
        if (lev < 10) {
            phase_M2(A, tile, t, lev);  b_arrive(A.cnt);  ++phA;
            b_wait(Bc.cnt, NPBAR * phB);
            phase_M2(Bc, tile, t, lev); b_arrive(Bc.cnt); ++phB;
            b_wait(A.cnt, NPBAR * phA);
        } else {
            phase_M3(A, tile, t, bA, out);
            b_wait(Bc.cnt, NPBAR * phB);
            phase_M3(Bc, tile, t, bB, out);
        }
    }
}

extern "C" void kernel_launch(void* const* d_in, const int* in_sizes, int n_in,
                              void* d_out, int out_size, void* d_ws, size_t ws_size,
                              hipStream_t stream)
{
    const float* xyz1 = (const float*)d_in[0];
    const float* xyz2 = (const float*)d_in[1];
    float* out = (float*)d_out;
    float* ws  = (float*)d_ws;

    hipMemsetAsync(d_out, 0, B_ * sizeof(float), stream);
    emd_init<<<BN / TPB, TPB, 0, stream>>>(xyz1, xyz2, ws);
    emd_main<<<NBLK, TPB, 0, stream>>>(ws, out);
}

// Round 9
// 319.810 us; speedup vs baseline: 1.6159x; 1.6159x over previous
//
#include <hip/hip_runtime.h>
#include <math.h>

typedef float f2 __attribute__((ext_vector_type(2)));

static constexpr int   B_   = 8;
static constexpr int   N_   = 2048;   // points per set
static constexpr int   TPB  = 256;
static constexpr int   TILE = 16;     // rows/cols owned per block
static constexpr int   BPB  = 128;    // blocks per batch
static constexpr int   NBLK = B_ * BPB;   // 1024 blocks = 4/CU exactly
static constexpr int   BN   = B_ * N_;
static constexpr float EPS_ = 1e-9f;
static constexpr float LOG2E = 1.4426950408889634f;

// ws layout (floats):
#define WS_X1    (ws)            // [4*BN] packed xyz1 (x,y,z,|p|^2)
#define WS_X2    (ws + 4*BN)     // [4*BN] packed xyz2
#define WS_SATL  (ws + 8*BN)
#define WS_SATR  (ws + 9*BN)
#define WS_SCAL  (ws + 10*BN)    // raw row scale
#define WS_LSCAL (ws + 11*BN)    // log2(scale)
#define WS_LSATR (ws + 12*BN)    // log2(satr)
#define WS_LWR   (ws + 13*BN)    // log2(wr)
#define WS_WR    (ws + 14*BN)    // raw wr
#define WS_COST  (ws + 15*BN)

__global__ void __launch_bounds__(TPB)
emd_init(const float* __restrict__ xyz1, const float* __restrict__ xyz2,
         float* __restrict__ ws)
{
    const int idx = blockIdx.x * TPB + threadIdx.x;
    if (idx >= BN) return;
    float x = xyz1[idx*3], y = xyz1[idx*3+1], z = xyz1[idx*3+2];
    reinterpret_cast<float4*>(WS_X1)[idx] =
        make_float4(x, y, z, fmaf(x,x, fmaf(y,y, z*z)));
    x = xyz2[idx*3]; y = xyz2[idx*3+1]; z = xyz2[idx*3+2];
    reinterpret_cast<float4*>(WS_X2)[idx] =
        make_float4(x, y, z, fmaf(x,x, fmaf(y,y, z*z)));
    WS_SATL[idx]  = 1.f;
    WS_SATR[idx]  = 1.f;
    WS_LSATR[idx] = 0.f;
    WS_COST[idx]  = 0.f;
}

// fused reduction of NA arrays of 8 row-partials; rs[a] valid for t < 16.
// sc = 32KB scratch (overlays pts; leading sync covers last reader).
template<int NA>
__device__ __forceinline__ void reduce_multi(float* sc, const float (*s)[8],
                                             int t, float* rs)
{
    const int c = t >> 1, g = t & 1;
    __syncthreads();
#pragma unroll
    for (int a = 0; a < NA; ++a) {
        float* red = sc + a * 2176;     // [128][17]
#pragma unroll
        for (int j = 0; j < 8; ++j) red[c*17 + g*8 + j] = s[a][j];
    }
    __syncthreads();
    {
        const int col = t & 15, seg = t >> 4;
#pragma unroll
        for (int a = 0; a < NA; ++a) {
            const float* red = sc + a * 2176;
            float v = 0.f;
#pragma unroll
            for (int k = 0; k < 8; ++k) v += red[(seg*8 + k)*17 + col];
            sc[6528 + a*272 + seg*17 + col] = v;     // [16][17] per array
        }
    }
    __syncthreads();
    if (t < 16) {
#pragma unroll
        for (int a = 0; a < NA; ++a) {
            float r = 0.f;
#pragma unroll
            for (int q = 0; q < 16; ++q) r += sc[6528 + a*272 + q*17 + t];
            rs[a] = r;
        }
    }
}

// MODE 0: first row sweep  (stream x2, w = lv*p2 + lsatr(=0))  -> scal/lscal
// MODE 1: col sweep        (stream x1, w = lv*p2 + lscal)      -> satr/wr
// MODE 2: P3(lev)+P1(lev+1) row sweep (w = lvA*p2+lwr, aux = lvB*p2+lsatr)
// MODE 3: final row sweep  (w = raw wr)                        -> cost -> out
template<int MODE>
__global__ void __launch_bounds__(TPB, 4)
emd_pass(float* __restrict__ ws, float* __restrict__ out,
         const float lvA, const float lvB)
{
    constexpr int SMEM = (MODE == 2) ? 40960 : 32768;
    __shared__ __align__(16) char smem[SMEM];
    float4* pts  = reinterpret_cast<float4*>(smem);
    float*  auxB = reinterpret_cast<float*>(smem + 32768);  // MODE 2 only
    float*  sc   = reinterpret_cast<float*>(smem);          // reduce overlay

    const int b    = blockIdx.x >> 7;
    const int tile = blockIdx.x & 127;
    const int t    = threadIdx.x;

    const float4* x1v = reinterpret_cast<const float4*>(WS_X1) + b * N_;
    const float4* x2v = reinterpret_cast<const float4*>(WS_X2) + b * N_;
    const float* lscal = WS_LSCAL + b * N_;
    const float* lsatr = WS_LSATR + b * N_;
    const float* lwr   = WS_LWR   + b * N_;
    const float* wrp   = WS_WR    + b * N_;

    // ---- staging ----
    for (int p = t; p < N_; p += TPB) {
        if (MODE == 0) {
            float4 v = x2v[p];
            pts[p] = make_float4(v.x, v.y, v.z, lvB * v.w);
        } else if (MODE == 1) {
            float4 v = x1v[p];
            pts[p] = make_float4(v.x, v.y, v.z, fmaf(lvB, v.w, lscal[p]));
        } else if (MODE == 2) {
            float4 v = x2v[p];
            pts[p]  = make_float4(v.x, v.y, v.z, fmaf(lvA, v.w, lwr[p]));
            auxB[p] = fmaf(lvB, v.w, lsatr[p]);
        } else {
            float4 v = x2v[p];
            pts[p] = make_float4(v.x, v.y, v.z, wrp[p]);
        }
    }

    // ---- owned coefficients, packed in row pairs ----
    const float4* ownv = (MODE == 1) ? x2v : x1v;
    const int ob = tile * TILE + (t & 1) * 8;
    f2 kx[4], ky[4], kz[4], kc[4];
#pragma unroll
    for (int jp = 0; jp < 4; ++jp) {
        float4 v0 = ownv[ob + 2*jp], v1 = ownv[ob + 2*jp + 1];
        if (MODE == 0 || MODE == 1) {
            const float m2 = -2.f * lvB;
            kx[jp] = (f2){m2*v0.x, m2*v1.x};
            ky[jp] = (f2){m2*v0.y, m2*v1.y};
            kz[jp] = (f2){m2*v0.z, m2*v1.z};
            kc[jp] = (f2){lvB*v0.w, lvB*v1.w};
        } else {
            kx[jp] = (f2){-2.f*v0.x, -2.f*v1.x};
            ky[jp] = (f2){-2.f*v0.y, -2.f*v1.y};
            kz[jp] = (f2){-2.f*v0.z, -2.f*v1.z};
            kc[jp] = (f2){v0.w, v1.w};
        }
    }
    __syncthreads();

    // ---- sweep: 16 iters, 2-deep prefetch, packed dot products ----
    float s1[8], s2[8], s3[8];
#pragma unroll
    for (int j = 0; j < 8; ++j) { s1[j] = 0.f; s2[j] = 0.f; s3[j] = 0.f; }

    int l = t >> 1;
    float4 p = pts[l];
    float  ab = (MODE == 2) ? auxB[l] : 0.f;

#pragma unroll 2
    for (int i = 0; i < 16; ++i) {
        const int ln = (l + 128) & (N_ - 1);
        const float4 pn = pts[ln];
        float abn = 0.f;
        if (MODE == 2) abn = auxB[ln];

        const f2 px = (f2){p.x, p.x}, py = (f2){p.y, p.y}, pz = (f2){p.z, p.z};
        float p2s = 0.f;
        if (MODE == 2 || MODE == 3)
            p2s = fmaf(p.x, p.x, fmaf(p.y, p.y, p.z * p.z));

#pragma unroll
        for (int jp = 0; jp < 4; ++jp) {
            if (MODE == 0 || MODE == 1) {
                f2 a = kc[jp] + (f2){p.w, p.w};
                a = kz[jp] * pz + a;
                a = ky[jp] * py + a;
                a = kx[jp] * px + a;
                s1[2*jp]   += __builtin_amdgcn_exp2f(a.x);
                s1[2*jp+1] += __builtin_amdgcn_exp2f(a.y);
            } else if (MODE == 2) {
                f2 dq = kz[jp] * pz + kc[jp];
                dq = ky[jp] * py + dq;
                dq = kx[jp] * px + dq;                  // |q|^2 - 2 p.q
                const float d20 = dq.x + p2s, d21 = dq.y + p2s;
                const float sq0 = __builtin_amdgcn_sqrtf(fmaxf(d20, 0.f));
                const float sq1 = __builtin_amdgcn_sqrtf(fmaxf(d21, 0.f));
                const float eA0 = __builtin_amdgcn_exp2f(fmaf(lvA, dq.x, p.w));
                const float eA1 = __builtin_amdgcn_exp2f(fmaf(lvA, dq.y, p.w));
                const float eB0 = __builtin_amdgcn_exp2f(fmaf(lvB, dq.x, ab));
                const float eB1 = __builtin_amdgcn_exp2f(fmaf(lvB, dq.y, ab));
                s1[2*jp]   += eA0;            s1[2*jp+1] += eA1;
                s2[2*jp]    = fmaf(eA0, sq0, s2[2*jp]);
                s2[2*jp+1]  = fmaf(eA1, sq1, s2[2*jp+1]);
                s3[2*jp]   += eB0;            s3[2*jp+1] += eB1;
            } else {
                f2 dq = kz[jp] * pz + kc[jp];
                dq = ky[jp] * py + dq;
                dq = kx[jp] * px + dq;
                const float sq0 = __builtin_amdgcn_sqrtf(fmaxf(dq.x + p2s, 0.f));
                const float sq1 = __builtin_amdgcn_sqrtf(fmaxf(dq.y + p2s, 0.f));
                s2[2*jp]   = fmaf(p.w, sq0, s2[2*jp]);
                s2[2*jp+1] = fmaf(p.w, sq1, s2[2*jp+1]);
            }
        }
        p = pn; ab = abn; l = ln;
    }

    // ---- reductions + epilogue ----
    const int gidx = b * N_ + tile * TILE + t;   // valid for t < 16

    if (MODE == 0) {
        float rs[1];
        reduce_multi<1>(sc, &s1, t, rs);
        if (t < TILE) {
            const float scv = WS_SATL[gidx] / (rs[0] + EPS_);
            WS_SCAL[gidx]  = scv;
            WS_LSCAL[gidx] = __log2f(scv);
        }
    } else if (MODE == 1) {
        float rs[1];
        reduce_multi<1>(sc, &s1, t, rs);
        if (t < TILE) {
            const float sr  = WS_SATR[gidx];
            const float w1s = sr * rs[0];
            const float rr  = fminf(sr / (w1s + EPS_), 1.f);
            const float wrv = sr * rr;
            const float srn = fmaxf(sr - rr * w1s, 0.f);
            WS_SATR[gidx]  = srn;
            WS_WR[gidx]    = wrv;
            WS_LWR[gidx]   = __log2f(wrv);
            WS_LSATR[gidx] = __log2f(srn);
        }
    } else if (MODE == 2) {
        float sall[3][8];
#pragma unroll
        for (int j = 0; j < 8; ++j) {
            sall[0][j] = s1[j]; sall[1][j] = s2[j]; sall[2][j] = s3[j];
        }
        float rs[3];
        reduce_multi<3>(sc, sall, t, rs);
        if (t < TILE) {
            const float scp = WS_SCAL[gidx];
            const float sln = fmaxf(WS_SATL[gidx] - scp * rs[0], 0.f);
            WS_COST[gidx]   = fmaf(scp, rs[1], WS_COST[gidx]);
            const float scn = sln / (rs[2] + EPS_);
            WS_SATL[gidx]  = sln;
            WS_SCAL[gidx]  = scn;
            WS_LSCAL[gidx] = __log2f(scn);
        }
    } else {
        float rs[1];
        reduce_multi<1>(sc, &s2, t, rs);
        if (t < 16) {
            float v = fmaf(WS_SCAL[gidx], rs[0], WS_COST[gidx]);
#pragma unroll
            for (int k = 8; k >= 1; k >>= 1) v += __shfl_xor(v, k, 16);
            if (t == 0) atomicAdd(out + b, v);
        }
    }
}

extern "C" void kernel_launch(void* const* d_in, const int* in_sizes, int n_in,
                              void* d_out, int out_size, void* d_ws, size_t ws_size,
                              hipStream_t stream)
{
    const float* xyz1 = (const float*)d_in[0];
    const float* xyz2 = (const float*)d_in[1];
    float* out = (float*)d_out;
    float* ws  = (float*)d_ws;

    hipMemsetAsync(d_out, 0, B_ * sizeof(float), stream);
    emd_init<<<BN / TPB, TPB, 0, stream>>>(xyz1, xyz2, ws);

    static const float levels[11] = {
        -65536.f, -16384.f, -4096.f, -1024.f, -256.f,
        -64.f, -16.f, -4.f, -1.f, -0.25f, 0.f};

    emd_pass<0><<<NBLK, TPB, 0, stream>>>(ws, out, 0.f, levels[0] * LOG2E);
    emd_pass<1><<<NBLK, TPB, 0, stream>>>(ws, out, 0.f, levels[0] * LOG2E);
    for (int lev = 1; lev < 11; ++lev) {
        emd_pass<2><<<NBLK, TPB, 0, stream>>>(ws, out, levels[lev-1] * LOG2E,
                                                       levels[lev]   * LOG2E);
        emd_pass<1><<<NBLK, TPB, 0, stream>>>(ws, out, 0.f, levels[lev] * LOG2E);
    }
    emd_pass<3><<<NBLK, TPB, 0, stream>>>(ws, out, 0.f, 0.f);
}